// Round 7
// baseline (415.006 us; speedup 1.0000x reference)
//
#include <hip/hip_runtime.h>
#include <hip/hip_bf16.h>

// Problem constants
static constexpr int PN = 16384;  // paths
static constexpr int TT = 8;      // seq len
static constexpr int LN = 4096;   // links
static constexpr int KG = 16;     // path_to_link K
static constexpr int NN = 2048;   // nodes
static constexpr int K2G = 32;    // path_to_node K2
static constexpr int MG = 8;      // link_to_node M
static constexpr int ITER = 8;

typedef __attribute__((ext_vector_type(8))) short short8b;   // 8 bf16 (4 VGPRs)
typedef __attribute__((ext_vector_type(4))) float f32x4;
typedef __attribute__((ext_vector_type(4))) unsigned int u32x4;  // clang vector: OK for nontemporal builtins

__device__ __forceinline__ float frcp(float x) {
    return __builtin_amdgcn_rcpf(x);   // v_rcp_f32, ~1ulp
}
__device__ __forceinline__ float sigmoidf_(float x) {
    return frcp(1.0f + __expf(-x));
}
__device__ __forceinline__ float tanhf_(float x) {
    return 1.0f - 2.0f * frcp(__expf(2.0f * x) + 1.0f);
}
__device__ __forceinline__ float softplusf_(float x) {
    return fmaxf(x, 0.0f) + log1pf(__expf(-fabsf(x)));
}
__device__ __forceinline__ unsigned short f2bf(float f) {
    unsigned int x = __float_as_uint(f);
    unsigned int r = (x + 0x7fffu + ((x >> 16) & 1u)) >> 16;
    return (unsigned short)r;
}
// packed RNE f32x2 -> bf16x2 (v_cvt_pk_bf16_f32 on gfx950)
__device__ __forceinline__ unsigned int pk2bf(float a, float b) {
    union { __hip_bfloat162 h; unsigned int u; } cvt;
    cvt.h = __float22bfloat162_rn(float2{a, b});
    return cvt.u;
}
__device__ __forceinline__ float bf2f(unsigned short u) {
    return __uint_as_float(((unsigned int)u) << 16);
}

// ---------------------------------------------------------------------------
// K_setup: heterogeneous launch.
//   blocks [0,1024)    : path encoder, 16 rows/block, w2 in LDS
//   blocks [1024,1280) : link encoder, 16 rows/block, w2 in LDS (+bf16 mirror)
//   blocks [1280,1568) : 6x GRU weight transpose fp32[64][192]->bf16[192][64]
// ---------------------------------------------------------------------------
__global__ __launch_bounds__(256) void k_setup(
    const float* __restrict__ ft, const float* __restrict__ fpk,
    const float* __restrict__ fps, const float* __restrict__ cap,
    const int* __restrict__ ptl, const int* __restrict__ ldt,
    const float* __restrict__ pe_w1, const float* __restrict__ pe_b1,
    const float* __restrict__ pe_w2, const float* __restrict__ pe_b2,
    const float* __restrict__ le_w1, const float* __restrict__ le_b1,
    const float* __restrict__ le_w2, const float* __restrict__ le_b2,
    const float* __restrict__ pgru_wx, const float* __restrict__ pgru_wh,
    const float* __restrict__ lgru_wx, const float* __restrict__ lgru_wh,
    const float* __restrict__ dgru_wx, const float* __restrict__ dgru_wh,
    unsigned short* __restrict__ pwxT, unsigned short* __restrict__ pwhT,
    unsigned short* __restrict__ lwxT, unsigned short* __restrict__ lwhT,
    unsigned short* __restrict__ dwxT, unsigned short* __restrict__ dwhT,
    float* __restrict__ path_state, float* __restrict__ link_state,
    unsigned short* __restrict__ lsb)
{
    int b = blockIdx.x;
    int tid = threadIdx.x;
    if (b >= 1280) {
        const float* srcs[6] = {pgru_wx, pgru_wh, lgru_wx, lgru_wh, dgru_wx, dgru_wh};
        unsigned short* dsts[6] = {pwxT, pwhT, lwxT, lwhT, dwxT, dwhT};
        int i = (b - 1280) * 256 + tid;     // 0 .. 6*12288-1
        int mi = i / 12288, o = i - mi * 12288;
        int n = o >> 6, k = o & 63;
        dsts[mi][o] = f2bf(srcs[mi][k * 192 + n]);
        return;
    }
    __shared__ __align__(16) float w2s[4096];
    __shared__ float w1s[192], b1s[64], b2s[64];
    __shared__ float h1s[4][64];
    bool isPath = (b < 1024);
    const float* w1p = isPath ? pe_w1 : le_w1;
    const float* b1p = isPath ? pe_b1 : le_b1;
    const float* w2p = isPath ? pe_w2 : le_w2;
    const float* b2p = isPath ? pe_b2 : le_b2;
    for (int i = tid; i < 4096; i += 256) w2s[i] = w2p[i];
    if (tid < 192) w1s[tid] = w1p[tid];
    if (tid < 64) { b1s[tid] = b1p[tid]; b2s[tid] = b2p[tid]; }
    __syncthreads();
    int rl = tid >> 6, d = tid & 63;
    int base = (isPath ? b : (b - 1024)) * 16;
    for (int rp = 0; rp < 4; ++rp) {
        int row = base + rp * 4 + rl;
        float h;
        if (isPath) {
            float x0 = ft[row]  * 1e-4f;
            float x1 = fpk[row] * 1e-3f;
            float x2 = fps[row] * 1e-3f;
            h = b1s[d] + x0 * w1s[d] + x1 * w1s[64 + d] + x2 * w1s[128 + d];
        } else {
            float v = 0.0f;
            if (d < 16) v = ft[ptl[(row * 16 + d) * 2]];
            v += __shfl_down(v, 8);
            v += __shfl_down(v, 4);
            v += __shfl_down(v, 2);
            v += __shfl_down(v, 1);
            float ssum = __shfl(v, 0);
            float cv = cap[row];
            float load = ssum * frcp(cv * 1e9f);
            float x2 = (ldt[row] == 0) ? 1.0f : 0.0f;
            h = b1s[d] + cv * 0.01f * w1s[d] + load * w1s[64 + d] + x2 * w1s[128 + d];
        }
        h1s[rl][d] = fmaxf(h, 0.0f);
        __syncthreads();
        float acc = b2s[d];
#pragma unroll 8
        for (int k = 0; k < 64; ++k) acc += h1s[rl][k] * w2s[k * 64 + d];
        float v = fmaxf(acc, 0.0f);
        if (isPath) {
            path_state[(size_t)row * 64 + d] = v;
        } else {
            link_state[(size_t)row * 64 + d] = v;
            lsb[(size_t)row * 64 + d] = f2bf(v);   // bf16 mirror for pscan gather
        }
        __syncthreads();
    }
}

// ---------------------------------------------------------------------------
// K3: device encoder, w2 staged in LDS (+bf16 mirror)
// ---------------------------------------------------------------------------
__global__ __launch_bounds__(256) void k_device_encode(
    const float* __restrict__ link_state, const int* __restrict__ ltn,
    const int* __restrict__ nodes,
    const float* __restrict__ w1, const float* __restrict__ b1,
    const float* __restrict__ w2, const float* __restrict__ b2,
    float* __restrict__ device_state, unsigned short* __restrict__ dsb)
{
    __shared__ __align__(16) float w2s[4096];
    __shared__ float h1s[4][64];
    int tid = threadIdx.x;
    for (int i = tid; i < 4096; i += 256) w2s[i] = w2[i];
    int rl = tid >> 6, d = tid & 63;
    int row = blockIdx.x * 4 + rl;
    float s = 0.0f;
#pragma unroll
    for (int m = 0; m < MG; ++m)
        s += link_state[(size_t)ltn[row * MG + m] * 64 + d];
#pragma unroll
    for (int o = 32; o > 0; o >>= 1) s += __shfl_xor(s, o);
    float dlm = s * (1.0f / 64.0f);
    float enc = (nodes[row] == 0) ? 1.0f : 0.0f;
    float h = b1[d] + enc * w1[d] + dlm * w1[64 + d];
    h1s[rl][d] = fmaxf(h, 0.0f);
    __syncthreads();
    float acc = b2[d];
#pragma unroll 8
    for (int k = 0; k < 64; ++k) acc += h1s[rl][k] * w2s[k * 64 + d];
    float v = fmaxf(acc, 0.0f);
    device_state[(size_t)row * 64 + d] = v;
    dsb[(size_t)row * 64 + d] = f2bf(v);   // bf16 mirror for pscan gather
}

// ---------------------------------------------------------------------------
// K4: fused x-gather + xproj + 8-step GRU scan (+ fused readout when LAST).
// R7: TWO path-groups per block (32 paths, 512 blocks, 4 waves).
// Each wave carries two independent scan chains (A: paths p0..p0+15,
// B: p0+16..p0+31) between barriers: ONE barrier per step covers both
// groups' h-exchange, so the exchange stall is amortized over 2x work and
// the two dep chains (aH ds_read -> MFMA -> gates) interleave in-wave.
// Weight fragments shared across groups (no VGPR duplication).
// Evidence: R0-R6 showed store/gather/byte changes all neutral; only the
// sync-stall : work ratio has ever moved k_pscan's time (R3 vs R4/R5).
// ---------------------------------------------------------------------------
template <bool LAST>
__global__ __launch_bounds__(256, 2) void k_pscan(
    const unsigned short* __restrict__ lsb, const unsigned short* __restrict__ dsb,
    const int* __restrict__ ltp, const int* __restrict__ ntp,
    const unsigned short* __restrict__ wxT,   // bf16 [192][64]
    const unsigned short* __restrict__ whT,   // bf16 [192][64]
    const float* __restrict__ bx, const float* __restrict__ bh,
    float* __restrict__ path_state, unsigned short* __restrict__ pssb,
    const float* __restrict__ rw1, const float* __restrict__ rb1,
    const float* __restrict__ rw2, const float* __restrict__ rb2,
    const float* __restrict__ rw3, const float* __restrict__ rb3,
    const float* __restrict__ cap, float* __restrict__ out)
{
    __shared__ __align__(16) unsigned short Xs[2][8][16][72];  // per-group: bf16 x, then h_t
    __shared__ __align__(16) unsigned short Hb0[2][16][72];    // per-group: bf16 h_{-1} seed
    __shared__ int sIdx[2][256];                               // per-group: 128 pairs x {il,in}
    __shared__ __align__(16) float rw1s[LAST ? 2048 : 4];
    __shared__ __align__(16) float rw2s[LAST ? 512 : 4];
    __shared__ float rw3s[16], rb1s[32], rb2s[16];
    int tid = threadIdx.x;
    int p0 = blockIdx.x * 32;

    if (LAST) {
        for (int i = tid; i < 2048; i += 256) rw1s[i] = rw1[i];
        for (int i = tid; i < 512; i += 256) rw2s[i] = rw2[i];
        if (tid < 16) rw3s[tid] = rw3[tid];
        if (tid < 32) rb1s[tid] = rb1[tid];
        if (tid < 16) rb2s[tid] = rb2[tid];
    }
    // stage gather indices for both groups
#pragma unroll
    for (int g2 = 0; g2 < 2; ++g2) {
        int pi = tid >> 1;
        int m = pi & 15, t = pi >> 4;
        int gi = (p0 + g2 * 16 + m) * TT + t;
        sIdx[g2][tid] = (tid & 1) ? __builtin_nontemporal_load(ntp + gi)
                                  : __builtin_nontemporal_load(ltp + gi);
    }
    __syncthreads();
    // gather x = lsb[il] + dsb[in] (bf16 mirrors) -> Xs[g2][t][m][:]
    // 16 lanes per row; all loads per group issued back-to-back (MLP).
    {
        int j = tid & 15;          // 4-elem group within row
        int g = tid >> 4;          // row group 0..15
#pragma unroll
        for (int g2 = 0; g2 < 2; ++g2) {
            uint2 A[8], B[8];
#pragma unroll
            for (int ro = 0; ro < 8; ++ro) {
                int pi = ro * 16 + g;  // t = ro, m = g
                int il = sIdx[g2][pi * 2];
                int in = sIdx[g2][pi * 2 + 1];
                A[ro] = *(const uint2*)(lsb + (size_t)il * 64 + j * 4);
                B[ro] = *(const uint2*)(dsb + (size_t)in * 64 + j * 4);
            }
#pragma unroll
            for (int ro = 0; ro < 8; ++ro) {
                float a0 = bf2f((unsigned short)A[ro].x);
                float a1 = bf2f((unsigned short)(A[ro].x >> 16));
                float a2 = bf2f((unsigned short)A[ro].y);
                float a3 = bf2f((unsigned short)(A[ro].y >> 16));
                float b0 = bf2f((unsigned short)B[ro].x);
                float b1 = bf2f((unsigned short)(B[ro].x >> 16));
                float b2 = bf2f((unsigned short)B[ro].y);
                float b3 = bf2f((unsigned short)(B[ro].y >> 16));
                uint2 u;
                u.x = pk2bf(a0 + b0, a1 + b1);
                u.y = pk2bf(a2 + b2, a3 + b3);
                *(uint2*)&Xs[g2][ro][g][j * 4] = u;
            }
        }
    }

    int lane = tid & 63, w = tid >> 6;
    int c = lane & 15, q = lane >> 4;
    int d = 16 * w + c;
    short8b fx[3][2], fh[3][2];
#pragma unroll
    for (int g = 0; g < 3; ++g)
#pragma unroll
        for (int kt = 0; kt < 2; ++kt) {
            int off = (g * 64 + 16 * w + c) * 64 + kt * 32 + q * 8;
            fx[g][kt] = *(const short8b*)(wxT + off);
            fh[g][kt] = *(const short8b*)(whT + off);
        }
    float bz = bx[d] + bh[d];
    float br = bx[64 + d] + bh[64 + d];
    float bxc = bx[128 + d];
    float bhc = bh[128 + d];
    float holdA[4], holdB[4];
#pragma unroll
    for (int r_ = 0; r_ < 4; ++r_) {
        holdA[r_] = path_state[(size_t)(p0 + q * 4 + r_) * 64 + d];
        Hb0[0][q * 4 + r_][d] = f2bf(holdA[r_]);
        holdB[r_] = path_state[(size_t)(p0 + 16 + q * 4 + r_) * 64 + d];
        Hb0[1][q * 4 + r_][d] = f2bf(holdB[r_]);
    }
    __syncthreads();

    // aX prefetch registers, both groups
    short8b aXA0 = *(const short8b*)&Xs[0][0][c][q * 8];
    short8b aXA1 = *(const short8b*)&Xs[0][0][c][32 + q * 8];
    short8b aXB0 = *(const short8b*)&Xs[1][0][c][q * 8];
    short8b aXB1 = *(const short8b*)&Xs[1][0][c][32 + q * 8];

    for (int t = 0; t < TT; ++t) {
        f32x4 axA[3], ahA[3], axB[3], ahB[3];
        axA[0] = (f32x4){bz, bz, bz, bz};   axB[0] = axA[0];
        axA[1] = (f32x4){br, br, br, br};   axB[1] = axA[1];
        axA[2] = (f32x4){bxc, bxc, bxc, bxc}; axB[2] = axA[2];
        ahA[0] = (f32x4){0.f, 0.f, 0.f, 0.f}; ahB[0] = ahA[0];
        ahA[1] = (f32x4){0.f, 0.f, 0.f, 0.f}; ahB[1] = ahA[1];
        ahA[2] = (f32x4){bhc, bhc, bhc, bhc}; ahB[2] = ahA[2];
        const unsigned short* hA = (t == 0) ? &Hb0[0][0][0] : &Xs[0][t - 1][0][0];
        const unsigned short* hB = (t == 0) ? &Hb0[1][0][0] : &Xs[1][t - 1][0][0];
        short8b aHA0 = *(const short8b*)(hA + c * 72 + q * 8);
        short8b aHA1 = *(const short8b*)(hA + c * 72 + 32 + q * 8);
        short8b aHB0 = *(const short8b*)(hB + c * 72 + q * 8);
        short8b aHB1 = *(const short8b*)(hB + c * 72 + 32 + q * 8);
#pragma unroll
        for (int g = 0; g < 3; ++g) {
            axA[g] = __builtin_amdgcn_mfma_f32_16x16x32_bf16(aXA0, fx[g][0], axA[g], 0, 0, 0);
            axB[g] = __builtin_amdgcn_mfma_f32_16x16x32_bf16(aXB0, fx[g][0], axB[g], 0, 0, 0);
            axA[g] = __builtin_amdgcn_mfma_f32_16x16x32_bf16(aXA1, fx[g][1], axA[g], 0, 0, 0);
            axB[g] = __builtin_amdgcn_mfma_f32_16x16x32_bf16(aXB1, fx[g][1], axB[g], 0, 0, 0);
            ahA[g] = __builtin_amdgcn_mfma_f32_16x16x32_bf16(aHA0, fh[g][0], ahA[g], 0, 0, 0);
            ahB[g] = __builtin_amdgcn_mfma_f32_16x16x32_bf16(aHB0, fh[g][0], ahB[g], 0, 0, 0);
            ahA[g] = __builtin_amdgcn_mfma_f32_16x16x32_bf16(aHA1, fh[g][1], ahA[g], 0, 0, 0);
            ahB[g] = __builtin_amdgcn_mfma_f32_16x16x32_bf16(aHB1, fh[g][1], ahB[g], 0, 0, 0);
        }
        // prefetch next step's x fragments for both groups
        if (t < TT - 1) {
            aXA0 = *(const short8b*)&Xs[0][t + 1][c][q * 8];
            aXA1 = *(const short8b*)&Xs[0][t + 1][c][32 + q * 8];
            aXB0 = *(const short8b*)&Xs[1][t + 1][c][q * 8];
            aXB1 = *(const short8b*)&Xs[1][t + 1][c][32 + q * 8];
        }
#pragma unroll
        for (int r_ = 0; r_ < 4; ++r_) {
            float zA  = sigmoidf_(axA[0][r_] + ahA[0][r_]);
            float rrA = sigmoidf_(axA[1][r_] + ahA[1][r_]);
            float ccA = tanhf_(axA[2][r_] + rrA * ahA[2][r_]);
            float hnA = ccA + zA * (holdA[r_] - ccA);
            holdA[r_] = hnA;
            Xs[0][t][q * 4 + r_][d] = f2bf(hnA);
            float zB  = sigmoidf_(axB[0][r_] + ahB[0][r_]);
            float rrB = sigmoidf_(axB[1][r_] + ahB[1][r_]);
            float ccB = tanhf_(axB[2][r_] + rrB * ahB[2][r_]);
            float hnB = ccB + zB * (holdB[r_] - ccB);
            holdB[r_] = hnB;
            Xs[1][t][q * 4 + r_][d] = f2bf(hnB);
        }
        __syncthreads();
    }
    if (!LAST) {
#pragma unroll
        for (int r_ = 0; r_ < 4; ++r_) {
            path_state[(size_t)(p0 + q * 4 + r_) * 64 + d] = holdA[r_];
            path_state[(size_t)(p0 + 16 + q * 4 + r_) * 64 + d] = holdB[r_];
        }
        // bulk pssb store, block region = 32 paths x 8 steps x 128B contiguous
        {
            unsigned short* base = pssb + (size_t)p0 * TT * 64;
#pragma unroll
            for (int jj = 0; jj < 8; ++jj) {
                int o = jj * 2048 + tid * 8;   // ushort index, 0..16383
                int r = o >> 6;                // row = m*8 + t (m 0..31)
                int c0 = o & 63;
                int m = r >> 3, t = r & 7;
                int g2 = m >> 4, ml = m & 15;
                u32x4 v = *(const u32x4*)&Xs[g2][t][ml][c0];
                __builtin_nontemporal_store(v, (u32x4*)(base + o));
            }
        }
        return;
    }
    // ===== fused readout: Xs[g2][t][m][:] = h bf16, both groups =====
    {
        int r = tid >> 1, hh = tid & 1;      // row r = m*8 + t (m 0..15)
        int m = r >> 3, t = r & 7;
#pragma unroll
        for (int g2 = 0; g2 < 2; ++g2) {
            short8b rowv[8];
#pragma unroll
            for (int j = 0; j < 8; ++j)
                rowv[j] = *(const short8b*)&Xs[g2][t][m][j * 8];
            float a1[16];
#pragma unroll
            for (int i = 0; i < 16; ++i) a1[i] = 0.f;
#pragma unroll 4
            for (int k = 0; k < 64; ++k) {
                float x = bf2f((unsigned short)rowv[k >> 3][k & 7]);
                const float* wr = &rw1s[k * 32 + hh * 16];
                float4 wa = *(const float4*)(wr);
                float4 wb = *(const float4*)(wr + 4);
                float4 wc = *(const float4*)(wr + 8);
                float4 wd = *(const float4*)(wr + 12);
                a1[0]  += x * wa.x; a1[1]  += x * wa.y; a1[2]  += x * wa.z; a1[3]  += x * wa.w;
                a1[4]  += x * wb.x; a1[5]  += x * wb.y; a1[6]  += x * wb.z; a1[7]  += x * wb.w;
                a1[8]  += x * wc.x; a1[9]  += x * wc.y; a1[10] += x * wc.z; a1[11] += x * wc.w;
                a1[12] += x * wd.x; a1[13] += x * wd.y; a1[14] += x * wd.z; a1[15] += x * wd.w;
            }
#pragma unroll
            for (int i = 0; i < 16; ++i)
                a1[i] = fmaxf(a1[i] + rb1s[hh * 16 + i], 0.0f);
            float h1[32];
#pragma unroll
            for (int i = 0; i < 16; ++i) {
                float o = __shfl_xor(a1[i], 1);
                h1[hh * 16 + i] = a1[i];
                h1[(1 - hh) * 16 + i] = o;
            }
            float a2[8];
#pragma unroll
            for (int i = 0; i < 8; ++i) a2[i] = 0.f;
#pragma unroll 4
            for (int k = 0; k < 32; ++k) {
                float x = h1[k];
                const float* wr = &rw2s[k * 16 + hh * 8];
                float4 wa = *(const float4*)(wr);
                float4 wb = *(const float4*)(wr + 4);
                a2[0] += x * wa.x; a2[1] += x * wa.y; a2[2] += x * wa.z; a2[3] += x * wa.w;
                a2[4] += x * wb.x; a2[5] += x * wb.y; a2[6] += x * wb.z; a2[7] += x * wb.w;
            }
#pragma unroll
            for (int i = 0; i < 8; ++i)
                a2[i] = fmaxf(a2[i] + rb2s[hh * 8 + i], 0.0f);
            float h2[16];
#pragma unroll
            for (int i = 0; i < 8; ++i) {
                float o = __shfl_xor(a2[i], 1);
                h2[hh * 8 + i] = a2[i];
                h2[(1 - hh) * 8 + i] = o;
            }
            float a3 = rb3[0];
#pragma unroll
            for (int k = 0; k < 16; ++k) a3 += h2[k] * rw3s[k];
            float occ = softplusf_(a3);
            float dcon = occ * frcp(cap[ltp[(p0 + g2 * 16 + m) * TT + t]]);
            float s = dcon;
            s += __shfl_xor(s, 2);
            s += __shfl_xor(s, 4);
            s += __shfl_xor(s, 8);
            if ((tid & 15) == 0) out[p0 + g2 * 16 + m] = s;
        }
    }
}

// ---------------------------------------------------------------------------
// K6: merged link+device GRU update. Template Kg => fully unrolled gathers.
// Writes f32 state + bf16 mirror (consumed by next pscan's gather).
// ---------------------------------------------------------------------------
template <int Kg>
__device__ __forceinline__ void edge_body(
    const unsigned short* __restrict__ wxT, const unsigned short* __restrict__ whT,
    const float* __restrict__ bx, const float* __restrict__ bh,
    const int* __restrict__ p2e, const unsigned short* __restrict__ pssb,
    float* __restrict__ state, unsigned short* __restrict__ smir, int blk)
{
    __shared__ int idxs[16 * Kg * 2];
    __shared__ __align__(16) unsigned short Ab[16][72];
    __shared__ __align__(16) unsigned short Hbs[16][72];
    __shared__ __align__(16) float Hf[16][68];
    int tid = threadIdx.x;
    int r0 = blk * 16;
    for (int i = tid; i < 16 * Kg * 2; i += 256)
        idxs[i] = p2e[(size_t)r0 * Kg * 2 + i];
    __syncthreads();
    {
        int r = tid >> 4, c4 = (tid & 15) * 4;
        int row = r0 + r;
        float4 s = {0.f, 0.f, 0.f, 0.f};
#pragma unroll
        for (int k = 0; k < Kg; ++k) {
            int pi = idxs[(r * Kg + k) * 2];
            int ti = idxs[(r * Kg + k) * 2 + 1];
            ushort4 v = *(const ushort4*)(pssb + ((size_t)pi * TT + ti - 1) * 64 + c4);
            s.x += bf2f(v.x); s.y += bf2f(v.y);
            s.z += bf2f(v.z); s.w += bf2f(v.w);
        }
        uint2 ua;
        ua.x = pk2bf(s.x, s.y); ua.y = pk2bf(s.z, s.w);
        *(uint2*)&Ab[r][c4] = ua;
        float4 hv = *(const float4*)(state + (size_t)row * 64 + c4);
        *(float4*)&Hf[r][c4] = hv;
        uint2 uh;
        uh.x = pk2bf(hv.x, hv.y); uh.y = pk2bf(hv.z, hv.w);
        *(uint2*)&Hbs[r][c4] = uh;
    }
    __syncthreads();
    int lane = tid & 63, w = tid >> 6;
    int c = lane & 15, q = lane >> 4;
    int d = 16 * w + c;
    short8b fx[3][2], fh[3][2];
#pragma unroll
    for (int g = 0; g < 3; ++g)
#pragma unroll
        for (int kt = 0; kt < 2; ++kt) {
            int off = (g * 64 + 16 * w + c) * 64 + kt * 32 + q * 8;
            fx[g][kt] = *(const short8b*)(wxT + off);
            fh[g][kt] = *(const short8b*)(whT + off);
        }
    float bz = bx[d] + bh[d];
    float br = bx[64 + d] + bh[64 + d];
    float bxc = bx[128 + d];
    float bhc = bh[128 + d];
    f32x4 ax[3], ah[3];
    ax[0] = (f32x4){bz, bz, bz, bz};
    ax[1] = (f32x4){br, br, br, br};
    ax[2] = (f32x4){bxc, bxc, bxc, bxc};
    ah[0] = (f32x4){0.f, 0.f, 0.f, 0.f};
    ah[1] = (f32x4){0.f, 0.f, 0.f, 0.f};
    ah[2] = (f32x4){bhc, bhc, bhc, bhc};
#pragma unroll
    for (int kt = 0; kt < 2; ++kt) {
        short8b aA = *(const short8b*)&Ab[c][kt * 32 + q * 8];
        short8b aH = *(const short8b*)&Hbs[c][kt * 32 + q * 8];
#pragma unroll
        for (int g = 0; g < 3; ++g) {
            ax[g] = __builtin_amdgcn_mfma_f32_16x16x32_bf16(aA, fx[g][kt], ax[g], 0, 0, 0);
            ah[g] = __builtin_amdgcn_mfma_f32_16x16x32_bf16(aH, fh[g][kt], ah[g], 0, 0, 0);
        }
    }
#pragma unroll
    for (int r = 0; r < 4; ++r) {
        int m = q * 4 + r;
        float z  = sigmoidf_(ax[0][r] + ah[0][r]);
        float rr = sigmoidf_(ax[1][r] + ah[1][r]);
        float cc = tanhf_(ax[2][r] + rr * ah[2][r]);
        float hn = cc + z * (Hf[m][d] - cc);
        state[(size_t)(r0 + m) * 64 + d] = hn;
        smir[(size_t)(r0 + m) * 64 + d] = f2bf(hn);
    }
}

__global__ __launch_bounds__(256) void k_edge_merged(
    const unsigned short* __restrict__ lwxT, const unsigned short* __restrict__ lwhT,
    const float* __restrict__ lbx, const float* __restrict__ lbh,
    const int* __restrict__ ptl,
    const unsigned short* __restrict__ dwxT, const unsigned short* __restrict__ dwhT,
    const float* __restrict__ dbx, const float* __restrict__ dbh,
    const int* __restrict__ ptn,
    const unsigned short* __restrict__ pssb,
    float* __restrict__ link_state, float* __restrict__ device_state,
    unsigned short* __restrict__ lsb, unsigned short* __restrict__ dsb)
{
    int b = blockIdx.x;
    if (b < LN / 16) {
        edge_body<KG>(lwxT, lwhT, lbx, lbh, ptl, pssb, link_state, lsb, b);
    } else {
        edge_body<K2G>(dwxT, dwhT, dbx, dbh, ptn, pssb, device_state, dsb, b - LN / 16);
    }
}

// ---------------------------------------------------------------------------
extern "C" void kernel_launch(void* const* d_in, const int* in_sizes, int n_in,
                              void* d_out, int out_size, void* d_ws, size_t ws_size,
                              hipStream_t stream) {
    const float* ft   = (const float*)d_in[0];
    const float* fpk  = (const float*)d_in[1];
    const float* fps  = (const float*)d_in[2];
    const float* cap  = (const float*)d_in[3];
    const float* pe_w1 = (const float*)d_in[4];
    const float* pe_b1 = (const float*)d_in[5];
    const float* pe_w2 = (const float*)d_in[6];
    const float* pe_b2 = (const float*)d_in[7];
    const float* le_w1 = (const float*)d_in[8];
    const float* le_b1 = (const float*)d_in[9];
    const float* le_w2 = (const float*)d_in[10];
    const float* le_b2 = (const float*)d_in[11];
    const float* de_w1 = (const float*)d_in[12];
    const float* de_b1 = (const float*)d_in[13];
    const float* de_w2 = (const float*)d_in[14];
    const float* de_b2 = (const float*)d_in[15];
    const float* pgru_wx = (const float*)d_in[16];
    const float* pgru_wh = (const float*)d_in[17];
    const float* pgru_bx = (const float*)d_in[18];
    const float* pgru_bh = (const float*)d_in[19];
    const float* lgru_wx = (const float*)d_in[20];
    const float* lgru_wh = (const float*)d_in[21];
    const float* lgru_bx = (const float*)d_in[22];
    const float* lgru_bh = (const float*)d_in[23];
    const float* dgru_wx = (const float*)d_in[24];
    const float* dgru_wh = (const float*)d_in[25];
    const float* dgru_bx = (const float*)d_in[26];
    const float* dgru_bh = (const float*)d_in[27];
    const float* ro_w1 = (const float*)d_in[28];
    const float* ro_b1 = (const float*)d_in[29];
    const float* ro_w2 = (const float*)d_in[30];
    const float* ro_b2 = (const float*)d_in[31];
    const float* ro_w3 = (const float*)d_in[32];
    const float* ro_b3 = (const float*)d_in[33];
    const int* ltp   = (const int*)d_in[34];
    const int* ntp   = (const int*)d_in[35];
    const int* ptl   = (const int*)d_in[36];
    const int* ptn   = (const int*)d_in[37];
    const int* ltn   = (const int*)d_in[38];
    const int* nodes = (const int*)d_in[39];
    const int* ldt   = (const int*)d_in[40];
    float* out = (float*)d_out;

    char* ws = (char*)d_ws;
    float* path_state = (float*)ws;      ws += (size_t)PN * 64 * 4;
    float* link_state = (float*)ws;      ws += (size_t)LN * 64 * 4;
    float* device_state = (float*)ws;    ws += (size_t)NN * 64 * 4;
    unsigned short* pssb = (unsigned short*)ws; ws += (size_t)PN * TT * 64 * 2;
    unsigned short* lsb  = (unsigned short*)ws; ws += (size_t)LN * 64 * 2;
    unsigned short* dsb  = (unsigned short*)ws; ws += (size_t)NN * 64 * 2;
    unsigned short* pwxT = (unsigned short*)ws; ws += 192 * 64 * 2;
    unsigned short* pwhT = (unsigned short*)ws; ws += 192 * 64 * 2;
    unsigned short* lwxT = (unsigned short*)ws; ws += 192 * 64 * 2;
    unsigned short* lwhT = (unsigned short*)ws; ws += 192 * 64 * 2;
    unsigned short* dwxT = (unsigned short*)ws; ws += 192 * 64 * 2;
    unsigned short* dwhT = (unsigned short*)ws; ws += 192 * 64 * 2;

    k_setup<<<1568, 256, 0, stream>>>(ft, fpk, fps, cap, ptl, ldt,
                                      pe_w1, pe_b1, pe_w2, pe_b2,
                                      le_w1, le_b1, le_w2, le_b2,
                                      pgru_wx, pgru_wh, lgru_wx, lgru_wh,
                                      dgru_wx, dgru_wh,
                                      pwxT, pwhT, lwxT, lwhT, dwxT, dwhT,
                                      path_state, link_state, lsb);
    k_device_encode<<<NN / 4, 256, 0, stream>>>(link_state, ltn, nodes, de_w1,
                                                de_b1, de_w2, de_b2, device_state, dsb);
    for (int it = 0; it < ITER - 1; ++it) {
        k_pscan<false><<<PN / 32, 256, 0, stream>>>(
            lsb, dsb, ltp, ntp, pwxT, pwhT, pgru_bx, pgru_bh,
            path_state, pssb, ro_w1, ro_b1, ro_w2, ro_b2, ro_w3, ro_b3, cap, out);
        k_edge_merged<<<LN / 16 + NN / 16, 256, 0, stream>>>(
            lwxT, lwhT, lgru_bx, lgru_bh, ptl,
            dwxT, dwhT, dgru_bx, dgru_bh, ptn,
            pssb, link_state, device_state, lsb, dsb);
    }
    // final iteration: pscan + fused readout (edge update after it is dead work)
    k_pscan<true><<<PN / 32, 256, 0, stream>>>(
        lsb, dsb, ltp, ntp, pwxT, pwhT, pgru_bx, pgru_bh,
        path_state, pssb, ro_w1, ro_b1, ro_w2, ro_b2, ro_w3, ro_b3, cap, out);
}

// Round 9
// 385.336 us; speedup vs baseline: 1.0770x; 1.0770x over previous
//
#include <hip/hip_runtime.h>
#include <hip/hip_bf16.h>

// Problem constants
static constexpr int PN = 16384;  // paths
static constexpr int TT = 8;      // seq len
static constexpr int LN = 4096;   // links
static constexpr int KG = 16;     // path_to_link K
static constexpr int NN = 2048;   // nodes
static constexpr int K2G = 32;    // path_to_node K2
static constexpr int MG = 8;      // link_to_node M
static constexpr int ITER = 8;

typedef __attribute__((ext_vector_type(8))) short short8b;   // 8 bf16 (4 VGPRs)
typedef __attribute__((ext_vector_type(4))) float f32x4;
typedef __attribute__((ext_vector_type(4))) unsigned int u32x4;

__device__ __forceinline__ float frcp(float x) {
    return __builtin_amdgcn_rcpf(x);
}
__device__ __forceinline__ float sigmoidf_(float x) {
    return frcp(1.0f + __expf(-x));
}
__device__ __forceinline__ float tanhf_(float x) {
    return 1.0f - 2.0f * frcp(__expf(2.0f * x) + 1.0f);
}
__device__ __forceinline__ float softplusf_(float x) {
    return fmaxf(x, 0.0f) + log1pf(__expf(-fabsf(x)));
}
__device__ __forceinline__ unsigned short f2bf(float f) {
    unsigned int x = __float_as_uint(f);
    unsigned int r = (x + 0x7fffu + ((x >> 16) & 1u)) >> 16;
    return (unsigned short)r;
}
__device__ __forceinline__ unsigned int pk2bf(float a, float b) {
    union { __hip_bfloat162 h; unsigned int u; } cvt;
    cvt.h = __float22bfloat162_rn(float2{a, b});
    return cvt.u;
}
__device__ __forceinline__ float bf2f(unsigned short u) {
    return __uint_as_float(((unsigned int)u) << 16);
}

// ===========================================================================
// Manual grid barrier (regular launch; no cooperative API).
// Generation counter: no reset needed between barriers; cnt returns to 0.
// cnt/gen are memset to 0 before the kernel (replayed with the graph).
// Correct under graph replay and rocprof counter replays.
// ===========================================================================
__device__ __forceinline__ void gridbar(unsigned* cnt, unsigned* gen, unsigned nb) {
    __syncthreads();
    if (threadIdx.x == 0) {
        __threadfence();   // release: prior global writes visible after acquire
        unsigned g = __hip_atomic_load(gen, __ATOMIC_ACQUIRE, __HIP_MEMORY_SCOPE_AGENT);
        unsigned a = __hip_atomic_fetch_add(cnt, 1u, __ATOMIC_ACQ_REL, __HIP_MEMORY_SCOPE_AGENT);
        if (a + 1u == nb) {
            __hip_atomic_store(cnt, 0u, __ATOMIC_RELAXED, __HIP_MEMORY_SCOPE_AGENT);
            __hip_atomic_store(gen, g + 1u, __ATOMIC_RELEASE, __HIP_MEMORY_SCOPE_AGENT);
        } else {
            unsigned cur;
            do {
                __builtin_amdgcn_s_sleep(2);
                cur = __hip_atomic_load(gen, __ATOMIC_ACQUIRE, __HIP_MEMORY_SCOPE_AGENT);
            } while (cur == g);
        }
        __threadfence();   // acquire side for subsequent reads
    }
    __syncthreads();
}

struct KArgs {
    const float *ft, *fpk, *fps, *cap;
    const int *ldt;
    const float *pe_w1, *pe_b1, *pe_w2, *pe_b2;
    const float *le_w1, *le_b1, *le_w2, *le_b2;
    const float *de_w1, *de_b1, *de_w2, *de_b2;
    const float *pgru_wx, *pgru_wh, *pgru_bx, *pgru_bh;
    const float *lgru_wx, *lgru_wh, *lgru_bx, *lgru_bh;
    const float *dgru_wx, *dgru_wh, *dgru_bx, *dgru_bh;
    const float *ro_w1, *ro_b1, *ro_w2, *ro_b2, *ro_w3, *ro_b3;
    const int *ltp, *ntp, *ptl, *ptn, *ltn, *nodes;
    float *out;
    float *path_state, *link_state, *device_state;
    unsigned short *pssb, *lsb, *dsb;
    unsigned short *pwxT, *pwhT, *lwxT, *lwhT, *dwxT, *dwhT;
    unsigned *bar_cnt, *bar_gen;
};

// LDS union layout (bytes), total 32256 (4 blocks/CU):
//  encoder : w2s[4096]f @0 | w1s[192]f @16384 | b1s @17152 | b2s @17408 | h1s @17664(..18688)
//  pscan   : Xs[8][16][72]u16 @0(..18432) | Hb0[16][72]u16 @18432(..20736) | sIdx[256]i @20736 |
//            rw1s[2048]f @21760 | rw2s[512]f @29952 | rw3s @32000 | rb1s @32064 | rb2s @32192
//  edge    : idxs[1024]i @0 | Ab @4096 | Hbs @6400 | Hf @8704(..13056)
//  sIdx/rw* staged ONCE (untouched by encoder/edge); h1s-Hb0 overlap is dead-range only.
static constexpr int SMEM_BYTES = 32256;

template <int Kg>
__device__ __forceinline__ void edge_body_f(
    char* smem, int tid,
    const unsigned short* __restrict__ wxT, const unsigned short* __restrict__ whT,
    const float* __restrict__ bx, const float* __restrict__ bh,
    const int* __restrict__ p2e, const unsigned short* __restrict__ pssb,
    float* __restrict__ state, unsigned short* __restrict__ smir, int blk)
{
    int* idxs = (int*)smem;
    unsigned short (*Ab)[72]  = (unsigned short(*)[72])(smem + 4096);
    unsigned short (*Hbs)[72] = (unsigned short(*)[72])(smem + 6400);
    float (*Hf)[68] = (float(*)[68])(smem + 8704);
    int r0 = blk * 16;
    for (int i = tid; i < 16 * Kg * 2; i += 256)
        idxs[i] = p2e[(size_t)r0 * Kg * 2 + i];
    __syncthreads();
    {
        int r = tid >> 4, c4 = (tid & 15) * 4;
        int row = r0 + r;
        float4 s = {0.f, 0.f, 0.f, 0.f};
#pragma unroll
        for (int k = 0; k < Kg; ++k) {
            int pi = idxs[(r * Kg + k) * 2];
            int ti = idxs[(r * Kg + k) * 2 + 1];
            ushort4 v = *(const ushort4*)(pssb + ((size_t)pi * TT + ti - 1) * 64 + c4);
            s.x += bf2f(v.x); s.y += bf2f(v.y);
            s.z += bf2f(v.z); s.w += bf2f(v.w);
        }
        uint2 ua;
        ua.x = pk2bf(s.x, s.y); ua.y = pk2bf(s.z, s.w);
        *(uint2*)&Ab[r][c4] = ua;
        float4 hv = *(const float4*)(state + (size_t)row * 64 + c4);
        *(float4*)&Hf[r][c4] = hv;
        uint2 uh;
        uh.x = pk2bf(hv.x, hv.y); uh.y = pk2bf(hv.z, hv.w);
        *(uint2*)&Hbs[r][c4] = uh;
    }
    __syncthreads();
    int lane = tid & 63, w = tid >> 6;
    int c = lane & 15, q = lane >> 4;
    int d = 16 * w + c;
    short8b fx[3][2], fh[3][2];
#pragma unroll
    for (int g = 0; g < 3; ++g)
#pragma unroll
        for (int kt = 0; kt < 2; ++kt) {
            int off = (g * 64 + 16 * w + c) * 64 + kt * 32 + q * 8;
            fx[g][kt] = *(const short8b*)(wxT + off);
            fh[g][kt] = *(const short8b*)(whT + off);
        }
    float bz = bx[d] + bh[d];
    float br = bx[64 + d] + bh[64 + d];
    float bxc = bx[128 + d];
    float bhc = bh[128 + d];
    f32x4 ax[3], ah[3];
    ax[0] = (f32x4){bz, bz, bz, bz};
    ax[1] = (f32x4){br, br, br, br};
    ax[2] = (f32x4){bxc, bxc, bxc, bxc};
    ah[0] = (f32x4){0.f, 0.f, 0.f, 0.f};
    ah[1] = (f32x4){0.f, 0.f, 0.f, 0.f};
    ah[2] = (f32x4){bhc, bhc, bhc, bhc};
#pragma unroll
    for (int kt = 0; kt < 2; ++kt) {
        short8b aA = *(const short8b*)&Ab[c][kt * 32 + q * 8];
        short8b aH = *(const short8b*)&Hbs[c][kt * 32 + q * 8];
#pragma unroll
        for (int g = 0; g < 3; ++g) {
            ax[g] = __builtin_amdgcn_mfma_f32_16x16x32_bf16(aA, fx[g][kt], ax[g], 0, 0, 0);
            ah[g] = __builtin_amdgcn_mfma_f32_16x16x32_bf16(aH, fh[g][kt], ah[g], 0, 0, 0);
        }
    }
#pragma unroll
    for (int r = 0; r < 4; ++r) {
        int m = q * 4 + r;
        float z  = sigmoidf_(ax[0][r] + ah[0][r]);
        float rr = sigmoidf_(ax[1][r] + ah[1][r]);
        float cc = tanhf_(ax[2][r] + rr * ah[2][r]);
        float hn = cc + z * (Hf[m][d] - cc);
        state[(size_t)(r0 + m) * 64 + d] = hn;
        smir[(size_t)(r0 + m) * 64 + d] = f2bf(hn);
    }
}

// ---------------------------------------------------------------------------
// Fused persistent kernel: 1024 blocks x 256 threads (4/CU), regular launch,
// manual grid barrier. Replaces 16 dispatches with 1. hold stays in registers
// across all 8 iterations (path_state round-trips deleted).
// ---------------------------------------------------------------------------
__global__ __launch_bounds__(256, 4) void k_fused(KArgs A)
{
    __shared__ __align__(16) char smem[SMEM_BYTES];
    const int bid = blockIdx.x;
    const int tid = threadIdx.x;
    const int p0 = bid * 16;
    const unsigned NB = gridDim.x;

    const int lane = tid & 63, w = tid >> 6;
    const int c = lane & 15, q = lane >> 4;
    const int d = 16 * w + c;

    float* w2s = (float*)smem;
    float* w1s = (float*)(smem + 16384);
    float* b1s = (float*)(smem + 17152);
    float* b2s = (float*)(smem + 17408);
    float (*h1s)[64] = (float(*)[64])(smem + 17664);

    unsigned short (*Xs)[16][72] = (unsigned short(*)[16][72])smem;
    unsigned short (*Hb0)[72]    = (unsigned short(*)[72])(smem + 18432);
    int*   sIdx = (int*)(smem + 20736);
    float* rw1s = (float*)(smem + 21760);
    float* rw2s = (float*)(smem + 29952);
    float* rw3s = (float*)(smem + 32000);
    float* rb1s = (float*)(smem + 32064);
    float* rb2s = (float*)(smem + 32192);

    // ---- one-time staging: gather indices + readout weights (persist) ----
    {
        int pi = tid >> 1;
        int m = pi & 15, t = pi >> 4;
        int gi = (p0 + m) * TT + t;
        sIdx[tid] = (tid & 1) ? A.ntp[gi] : A.ltp[gi];
        for (int i = tid; i < 2048; i += 256) rw1s[i] = A.ro_w1[i];
        for (int i = tid; i < 512; i += 256) rw2s[i] = A.ro_w2[i];
        if (tid < 16) rw3s[tid] = A.ro_w3[tid];
        if (tid < 32) rb1s[tid] = A.ro_b1[tid];
        if (tid < 16) rb2s[tid] = A.ro_b2[tid];
    }

    // ---- P0a: path encoder (every block: its 16 paths) ----
    {
        for (int i = tid; i < 4096; i += 256) w2s[i] = A.pe_w2[i];
        if (tid < 192) w1s[tid] = A.pe_w1[tid];
        if (tid < 64) { b1s[tid] = A.pe_b1[tid]; b2s[tid] = A.pe_b2[tid]; }
        __syncthreads();
        int rl = tid >> 6, dd = tid & 63;
        for (int rp = 0; rp < 4; ++rp) {
            int row = p0 + rp * 4 + rl;
            float x0 = A.ft[row]  * 1e-4f;
            float x1 = A.fpk[row] * 1e-3f;
            float x2 = A.fps[row] * 1e-3f;
            float h = b1s[dd] + x0 * w1s[dd] + x1 * w1s[64 + dd] + x2 * w1s[128 + dd];
            h1s[rl][dd] = fmaxf(h, 0.0f);
            __syncthreads();
            float acc = b2s[dd];
#pragma unroll 8
            for (int k = 0; k < 64; ++k) acc += h1s[rl][k] * w2s[k * 64 + dd];
            A.path_state[(size_t)row * 64 + dd] = fmaxf(acc, 0.0f);
            __syncthreads();
        }
    }
    // ---- P0b: link encoder (bid<256: 16 links each) ----
    if (bid < 256) {
        for (int i = tid; i < 4096; i += 256) w2s[i] = A.le_w2[i];
        if (tid < 192) w1s[tid] = A.le_w1[tid];
        if (tid < 64) { b1s[tid] = A.le_b1[tid]; b2s[tid] = A.le_b2[tid]; }
        __syncthreads();
        int rl = tid >> 6, dd = tid & 63;
        int base = bid * 16;
        for (int rp = 0; rp < 4; ++rp) {
            int row = base + rp * 4 + rl;
            float v = 0.0f;
            if (dd < 16) v = A.ft[A.ptl[(row * 16 + dd) * 2]];
            v += __shfl_down(v, 8);
            v += __shfl_down(v, 4);
            v += __shfl_down(v, 2);
            v += __shfl_down(v, 1);
            float ssum = __shfl(v, 0);
            float cv = A.cap[row];
            float load = ssum * frcp(cv * 1e9f);
            float x2 = (A.ldt[row] == 0) ? 1.0f : 0.0f;
            float h = b1s[dd] + cv * 0.01f * w1s[dd] + load * w1s[64 + dd] + x2 * w1s[128 + dd];
            h1s[rl][dd] = fmaxf(h, 0.0f);
            __syncthreads();
            float acc = b2s[dd];
#pragma unroll 8
            for (int k = 0; k < 64; ++k) acc += h1s[rl][k] * w2s[k * 64 + dd];
            float vv = fmaxf(acc, 0.0f);
            A.link_state[(size_t)row * 64 + dd] = vv;
            A.lsb[(size_t)row * 64 + dd] = f2bf(vv);
            __syncthreads();
        }
    }
    // ---- P0c: GRU weight transpose (bid in [256,544)) ----
    if (bid >= 256 && bid < 544) {
        const float* srcs[6] = {A.pgru_wx, A.pgru_wh, A.lgru_wx, A.lgru_wh, A.dgru_wx, A.dgru_wh};
        unsigned short* dsts[6] = {A.pwxT, A.pwhT, A.lwxT, A.lwhT, A.dwxT, A.dwhT};
        int i = (bid - 256) * 256 + tid;
        int mi = i / 12288, o = i - mi * 12288;
        int n = o >> 6, k = o & 63;
        dsts[mi][o] = f2bf(srcs[mi][k * 192 + n]);
    }
    gridbar(A.bar_cnt, A.bar_gen, NB);

    // ---- P1: device encoder (bid<512: 4 nodes each) ----
    if (bid < 512) {
        for (int i = tid; i < 4096; i += 256) w2s[i] = A.de_w2[i];
        int rl = tid >> 6, dd = tid & 63;
        int row = bid * 4 + rl;
        float s = 0.0f;
#pragma unroll
        for (int m = 0; m < MG; ++m)
            s += A.link_state[(size_t)A.ltn[row * MG + m] * 64 + dd];
#pragma unroll
        for (int o = 32; o > 0; o >>= 1) s += __shfl_xor(s, o);
        float dlm = s * (1.0f / 64.0f);
        float enc = (A.nodes[row] == 0) ? 1.0f : 0.0f;
        float h = A.de_b1[dd] + enc * A.de_w1[dd] + dlm * A.de_w1[64 + dd];
        h1s[rl][dd] = fmaxf(h, 0.0f);
        __syncthreads();
        float acc = A.de_b2[dd];
#pragma unroll 8
        for (int k = 0; k < 64; ++k) acc += h1s[rl][k] * w2s[k * 64 + dd];
        float v = fmaxf(acc, 0.0f);
        A.device_state[(size_t)row * 64 + dd] = v;
        A.dsb[(size_t)row * 64 + dd] = f2bf(v);
    }
    gridbar(A.bar_cnt, A.bar_gen, NB);

    // ---- persistent pscan state: biases + h in registers across iterations ----
    const float bz  = A.pgru_bx[d] + A.pgru_bh[d];
    const float brr = A.pgru_bx[64 + d] + A.pgru_bh[64 + d];
    const float bxc = A.pgru_bx[128 + d];
    const float bhc = A.pgru_bh[128 + d];
    float hold[4];
#pragma unroll
    for (int r_ = 0; r_ < 4; ++r_)
        hold[r_] = A.path_state[(size_t)(p0 + q * 4 + r_) * 64 + d];

    for (int it = 0; it < ITER; ++it) {
        const bool last = (it == ITER - 1);
        // gather x = lsb[il] + dsb[in] -> Xs[t][m][:]
        {
            int j = tid & 15;
            int g = tid >> 4;
            uint2 Av[8], Bv[8];
#pragma unroll
            for (int ro = 0; ro < 8; ++ro) {
                int pi = ro * 16 + g;
                int il = sIdx[pi * 2];
                int in = sIdx[pi * 2 + 1];
                Av[ro] = *(const uint2*)(A.lsb + (size_t)il * 64 + j * 4);
                Bv[ro] = *(const uint2*)(A.dsb + (size_t)in * 64 + j * 4);
            }
#pragma unroll
            for (int ro = 0; ro < 8; ++ro) {
                float a0 = bf2f((unsigned short)Av[ro].x);
                float a1 = bf2f((unsigned short)(Av[ro].x >> 16));
                float a2 = bf2f((unsigned short)Av[ro].y);
                float a3 = bf2f((unsigned short)(Av[ro].y >> 16));
                float b0 = bf2f((unsigned short)Bv[ro].x);
                float b1 = bf2f((unsigned short)(Bv[ro].x >> 16));
                float b2 = bf2f((unsigned short)Bv[ro].y);
                float b3 = bf2f((unsigned short)(Bv[ro].y >> 16));
                uint2 u;
                u.x = pk2bf(a0 + b0, a1 + b1);
                u.y = pk2bf(a2 + b2, a3 + b3);
                *(uint2*)&Xs[ro][g][j * 4] = u;
            }
        }
        short8b fx[3][2], fh[3][2];
#pragma unroll
        for (int g = 0; g < 3; ++g)
#pragma unroll
            for (int kt = 0; kt < 2; ++kt) {
                int off = (g * 64 + 16 * w + c) * 64 + kt * 32 + q * 8;
                fx[g][kt] = *(const short8b*)(A.pwxT + off);
                fh[g][kt] = *(const short8b*)(A.pwhT + off);
            }
#pragma unroll
        for (int r_ = 0; r_ < 4; ++r_)
            Hb0[q * 4 + r_][d] = f2bf(hold[r_]);
        __syncthreads();

        short8b aXc0 = *(const short8b*)&Xs[0][c][q * 8];
        short8b aXc1 = *(const short8b*)&Xs[0][c][32 + q * 8];
        for (int t = 0; t < TT; ++t) {
            f32x4 ax[3], ah[3];
            ax[0] = (f32x4){bz, bz, bz, bz};
            ax[1] = (f32x4){brr, brr, brr, brr};
            ax[2] = (f32x4){bxc, bxc, bxc, bxc};
            ah[0] = (f32x4){0.f, 0.f, 0.f, 0.f};
            ah[1] = (f32x4){0.f, 0.f, 0.f, 0.f};
            ah[2] = (f32x4){bhc, bhc, bhc, bhc};
            const unsigned short* hsrc = (t == 0) ? &Hb0[0][0] : &Xs[t - 1][0][0];
            short8b aH0 = *(const short8b*)(hsrc + c * 72 + q * 8);
            short8b aH1 = *(const short8b*)(hsrc + c * 72 + 32 + q * 8);
#pragma unroll
            for (int g = 0; g < 3; ++g) {
                ax[g] = __builtin_amdgcn_mfma_f32_16x16x32_bf16(aXc0, fx[g][0], ax[g], 0, 0, 0);
                ax[g] = __builtin_amdgcn_mfma_f32_16x16x32_bf16(aXc1, fx[g][1], ax[g], 0, 0, 0);
                ah[g] = __builtin_amdgcn_mfma_f32_16x16x32_bf16(aH0, fh[g][0], ah[g], 0, 0, 0);
                ah[g] = __builtin_amdgcn_mfma_f32_16x16x32_bf16(aH1, fh[g][1], ah[g], 0, 0, 0);
            }
            if (t < TT - 1) {
                aXc0 = *(const short8b*)&Xs[t + 1][c][q * 8];
                aXc1 = *(const short8b*)&Xs[t + 1][c][32 + q * 8];
            }
#pragma unroll
            for (int r_ = 0; r_ < 4; ++r_) {
                float z  = sigmoidf_(ax[0][r_] + ah[0][r_]);
                float rr = sigmoidf_(ax[1][r_] + ah[1][r_]);
                float cc = tanhf_(ax[2][r_] + rr * ah[2][r_]);
                float hn = cc + z * (hold[r_] - cc);
                hold[r_] = hn;
                Xs[t][q * 4 + r_][d] = f2bf(hn);
            }
            __syncthreads();
        }

        if (!last) {
            {
                unsigned short* base = A.pssb + (size_t)p0 * TT * 64;
#pragma unroll
                for (int jj = 0; jj < 4; ++jj) {
                    int o = jj * 2048 + tid * 8;
                    int r = o >> 6;
                    int c0 = o & 63;
                    int m = r >> 3, t = r & 7;
                    *(u32x4*)(base + o) = *(const u32x4*)&Xs[t][m][c0];
                }
            }
            gridbar(A.bar_cnt, A.bar_gen, NB);
            if (bid < LN / 16) {
                edge_body_f<KG>(smem, tid, A.lwxT, A.lwhT, A.lgru_bx, A.lgru_bh,
                                A.ptl, A.pssb, A.link_state, A.lsb, bid);
            } else if (bid < LN / 16 + NN / 16) {
                edge_body_f<K2G>(smem, tid, A.dwxT, A.dwhT, A.dgru_bx, A.dgru_bh,
                                 A.ptn, A.pssb, A.device_state, A.dsb, bid - LN / 16);
            }
            gridbar(A.bar_cnt, A.bar_gen, NB);
        } else {
            // ===== fused readout =====
            int r = tid >> 1, hh = tid & 1;
            int m = r >> 3, t = r & 7;
            short8b rowv[8];
#pragma unroll
            for (int j = 0; j < 8; ++j)
                rowv[j] = *(const short8b*)&Xs[t][m][j * 8];
            float a1[16];
#pragma unroll
            for (int i = 0; i < 16; ++i) a1[i] = 0.f;
#pragma unroll 4
            for (int k = 0; k < 64; ++k) {
                float x = bf2f((unsigned short)rowv[k >> 3][k & 7]);
                const float* wr = &rw1s[k * 32 + hh * 16];
                float4 wa = *(const float4*)(wr);
                float4 wb = *(const float4*)(wr + 4);
                float4 wc = *(const float4*)(wr + 8);
                float4 wd = *(const float4*)(wr + 12);
                a1[0]  += x * wa.x; a1[1]  += x * wa.y; a1[2]  += x * wa.z; a1[3]  += x * wa.w;
                a1[4]  += x * wb.x; a1[5]  += x * wb.y; a1[6]  += x * wb.z; a1[7]  += x * wb.w;
                a1[8]  += x * wc.x; a1[9]  += x * wc.y; a1[10] += x * wc.z; a1[11] += x * wc.w;
                a1[12] += x * wd.x; a1[13] += x * wd.y; a1[14] += x * wd.z; a1[15] += x * wd.w;
            }
#pragma unroll
            for (int i = 0; i < 16; ++i)
                a1[i] = fmaxf(a1[i] + rb1s[hh * 16 + i], 0.0f);
            float h1[32];
#pragma unroll
            for (int i = 0; i < 16; ++i) {
                float o = __shfl_xor(a1[i], 1);
                h1[hh * 16 + i] = a1[i];
                h1[(1 - hh) * 16 + i] = o;
            }
            float a2[8];
#pragma unroll
            for (int i = 0; i < 8; ++i) a2[i] = 0.f;
#pragma unroll 4
            for (int k = 0; k < 32; ++k) {
                float x = h1[k];
                const float* wr = &rw2s[k * 16 + hh * 8];
                float4 wa = *(const float4*)(wr);
                float4 wb = *(const float4*)(wr + 4);
                a2[0] += x * wa.x; a2[1] += x * wa.y; a2[2] += x * wa.z; a2[3] += x * wa.w;
                a2[4] += x * wb.x; a2[5] += x * wb.y; a2[6] += x * wb.z; a2[7] += x * wb.w;
            }
#pragma unroll
            for (int i = 0; i < 8; ++i)
                a2[i] = fmaxf(a2[i] + rb2s[hh * 8 + i], 0.0f);
            float h2[16];
#pragma unroll
            for (int i = 0; i < 8; ++i) {
                float o = __shfl_xor(a2[i], 1);
                h2[hh * 8 + i] = a2[i];
                h2[(1 - hh) * 8 + i] = o;
            }
            float a3 = A.ro_b3[0];
#pragma unroll
            for (int k = 0; k < 16; ++k) a3 += h2[k] * rw3s[k];
            float occ = softplusf_(a3);
            float dcon = occ * frcp(A.cap[sIdx[(t * 16 + m) * 2]]);
            float s = dcon;
            s += __shfl_xor(s, 2);
            s += __shfl_xor(s, 4);
            s += __shfl_xor(s, 8);
            if ((tid & 15) == 0) A.out[p0 + m] = s;
        }
    }
}

// ===========================================================================
// FALLBACK PATH: exact R6 multi-kernel pipeline (known-good, 388 us)
// ===========================================================================
__global__ __launch_bounds__(256) void k_setup(
    const float* __restrict__ ft, const float* __restrict__ fpk,
    const float* __restrict__ fps, const float* __restrict__ cap,
    const int* __restrict__ ptl, const int* __restrict__ ldt,
    const float* __restrict__ pe_w1, const float* __restrict__ pe_b1,
    const float* __restrict__ pe_w2, const float* __restrict__ pe_b2,
    const float* __restrict__ le_w1, const float* __restrict__ le_b1,
    const float* __restrict__ le_w2, const float* __restrict__ le_b2,
    const float* __restrict__ pgru_wx, const float* __restrict__ pgru_wh,
    const float* __restrict__ lgru_wx, const float* __restrict__ lgru_wh,
    const float* __restrict__ dgru_wx, const float* __restrict__ dgru_wh,
    unsigned short* __restrict__ pwxT, unsigned short* __restrict__ pwhT,
    unsigned short* __restrict__ lwxT, unsigned short* __restrict__ lwhT,
    unsigned short* __restrict__ dwxT, unsigned short* __restrict__ dwhT,
    float* __restrict__ path_state, float* __restrict__ link_state,
    unsigned short* __restrict__ lsb)
{
    int b = blockIdx.x;
    int tid = threadIdx.x;
    if (b >= 1280) {
        const float* srcs[6] = {pgru_wx, pgru_wh, lgru_wx, lgru_wh, dgru_wx, dgru_wh};
        unsigned short* dsts[6] = {pwxT, pwhT, lwxT, lwhT, dwxT, dwhT};
        int i = (b - 1280) * 256 + tid;
        int mi = i / 12288, o = i - mi * 12288;
        int n = o >> 6, k = o & 63;
        dsts[mi][o] = f2bf(srcs[mi][k * 192 + n]);
        return;
    }
    __shared__ __align__(16) float w2s[4096];
    __shared__ float w1s[192], b1s[64], b2s[64];
    __shared__ float h1s[4][64];
    bool isPath = (b < 1024);
    const float* w1p = isPath ? pe_w1 : le_w1;
    const float* b1p = isPath ? pe_b1 : le_b1;
    const float* w2p = isPath ? pe_w2 : le_w2;
    const float* b2p = isPath ? pe_b2 : le_b2;
    for (int i = tid; i < 4096; i += 256) w2s[i] = w2p[i];
    if (tid < 192) w1s[tid] = w1p[tid];
    if (tid < 64) { b1s[tid] = b1p[tid]; b2s[tid] = b2p[tid]; }
    __syncthreads();
    int rl = tid >> 6, d = tid & 63;
    int base = (isPath ? b : (b - 1024)) * 16;
    for (int rp = 0; rp < 4; ++rp) {
        int row = base + rp * 4 + rl;
        float h;
        if (isPath) {
            float x0 = ft[row]  * 1e-4f;
            float x1 = fpk[row] * 1e-3f;
            float x2 = fps[row] * 1e-3f;
            h = b1s[d] + x0 * w1s[d] + x1 * w1s[64 + d] + x2 * w1s[128 + d];
        } else {
            float v = 0.0f;
            if (d < 16) v = ft[ptl[(row * 16 + d) * 2]];
            v += __shfl_down(v, 8);
            v += __shfl_down(v, 4);
            v += __shfl_down(v, 2);
            v += __shfl_down(v, 1);
            float ssum = __shfl(v, 0);
            float cv = cap[row];
            float load = ssum * frcp(cv * 1e9f);
            float x2 = (ldt[row] == 0) ? 1.0f : 0.0f;
            h = b1s[d] + cv * 0.01f * w1s[d] + load * w1s[64 + d] + x2 * w1s[128 + d];
        }
        h1s[rl][d] = fmaxf(h, 0.0f);
        __syncthreads();
        float acc = b2s[d];
#pragma unroll 8
        for (int k = 0; k < 64; ++k) acc += h1s[rl][k] * w2s[k * 64 + d];
        float v = fmaxf(acc, 0.0f);
        if (isPath) {
            path_state[(size_t)row * 64 + d] = v;
        } else {
            link_state[(size_t)row * 64 + d] = v;
            lsb[(size_t)row * 64 + d] = f2bf(v);
        }
        __syncthreads();
    }
}

__global__ __launch_bounds__(256) void k_device_encode(
    const float* __restrict__ link_state, const int* __restrict__ ltn,
    const int* __restrict__ nodes,
    const float* __restrict__ w1, const float* __restrict__ b1,
    const float* __restrict__ w2, const float* __restrict__ b2,
    float* __restrict__ device_state, unsigned short* __restrict__ dsb)
{
    __shared__ __align__(16) float w2s[4096];
    __shared__ float h1s[4][64];
    int tid = threadIdx.x;
    for (int i = tid; i < 4096; i += 256) w2s[i] = w2[i];
    int rl = tid >> 6, d = tid & 63;
    int row = blockIdx.x * 4 + rl;
    float s = 0.0f;
#pragma unroll
    for (int m = 0; m < MG; ++m)
        s += link_state[(size_t)ltn[row * MG + m] * 64 + d];
#pragma unroll
    for (int o = 32; o > 0; o >>= 1) s += __shfl_xor(s, o);
    float dlm = s * (1.0f / 64.0f);
    float enc = (nodes[row] == 0) ? 1.0f : 0.0f;
    float h = b1[d] + enc * w1[d] + dlm * w1[64 + d];
    h1s[rl][d] = fmaxf(h, 0.0f);
    __syncthreads();
    float acc = b2[d];
#pragma unroll 8
    for (int k = 0; k < 64; ++k) acc += h1s[rl][k] * w2s[k * 64 + d];
    float v = fmaxf(acc, 0.0f);
    device_state[(size_t)row * 64 + d] = v;
    dsb[(size_t)row * 64 + d] = f2bf(v);
}

template <bool LAST>
__global__ __launch_bounds__(256, 4) void k_pscan(
    const unsigned short* __restrict__ lsb, const unsigned short* __restrict__ dsb,
    const int* __restrict__ ltp, const int* __restrict__ ntp,
    const unsigned short* __restrict__ wxT,
    const unsigned short* __restrict__ whT,
    const float* __restrict__ bx, const float* __restrict__ bh,
    float* __restrict__ path_state, unsigned short* __restrict__ pssb,
    const float* __restrict__ rw1, const float* __restrict__ rb1,
    const float* __restrict__ rw2, const float* __restrict__ rb2,
    const float* __restrict__ rw3, const float* __restrict__ rb3,
    const float* __restrict__ cap, float* __restrict__ out)
{
    __shared__ __align__(16) unsigned short Xs[8][16][72];
    __shared__ __align__(16) unsigned short Hb0[16][72];
    __shared__ int sIdx[256];
    __shared__ __align__(16) float rw1s[LAST ? 2048 : 4];
    __shared__ __align__(16) float rw2s[LAST ? 512 : 4];
    __shared__ float rw3s[16], rb1s[32], rb2s[16];
    int tid = threadIdx.x;
    int p0 = blockIdx.x * 16;

    if (LAST) {
        for (int i = tid; i < 2048; i += 256) rw1s[i] = rw1[i];
        for (int i = tid; i < 512; i += 256) rw2s[i] = rw2[i];
        if (tid < 16) rw3s[tid] = rw3[tid];
        if (tid < 32) rb1s[tid] = rb1[tid];
        if (tid < 16) rb2s[tid] = rb2[tid];
    }
    {
        int pi = tid >> 1;
        int m = pi & 15, t = pi >> 4;
        int gi = (p0 + m) * TT + t;
        sIdx[tid] = (tid & 1) ? __builtin_nontemporal_load(ntp + gi)
                              : __builtin_nontemporal_load(ltp + gi);
    }
    __syncthreads();
    {
        int j = tid & 15;
        int g = tid >> 4;
        uint2 A[8], B[8];
#pragma unroll
        for (int ro = 0; ro < 8; ++ro) {
            int pi = ro * 16 + g;
            int il = sIdx[pi * 2];
            int in = sIdx[pi * 2 + 1];
            A[ro] = *(const uint2*)(lsb + (size_t)il * 64 + j * 4);
            B[ro] = *(const uint2*)(dsb + (size_t)in * 64 + j * 4);
        }
#pragma unroll
        for (int ro = 0; ro < 8; ++ro) {
            float a0 = bf2f((unsigned short)A[ro].x);
            float a1 = bf2f((unsigned short)(A[ro].x >> 16));
            float a2 = bf2f((unsigned short)A[ro].y);
            float a3 = bf2f((unsigned short)(A[ro].y >> 16));
            float b0 = bf2f((unsigned short)B[ro].x);
            float b1 = bf2f((unsigned short)(B[ro].x >> 16));
            float b2 = bf2f((unsigned short)B[ro].y);
            float b3 = bf2f((unsigned short)(B[ro].y >> 16));
            uint2 u;
            u.x = pk2bf(a0 + b0, a1 + b1);
            u.y = pk2bf(a2 + b2, a3 + b3);
            *(uint2*)&Xs[ro][g][j * 4] = u;
        }
    }

    int lane = tid & 63, w = tid >> 6;
    int c = lane & 15, q = lane >> 4;
    int d = 16 * w + c;
    short8b fx[3][2], fh[3][2];
#pragma unroll
    for (int g = 0; g < 3; ++g)
#pragma unroll
        for (int kt = 0; kt < 2; ++kt) {
            int off = (g * 64 + 16 * w + c) * 64 + kt * 32 + q * 8;
            fx[g][kt] = *(const short8b*)(wxT + off);
            fh[g][kt] = *(const short8b*)(whT + off);
        }
    float bz = bx[d] + bh[d];
    float br = bx[64 + d] + bh[64 + d];
    float bxc = bx[128 + d];
    float bhc = bh[128 + d];
    float hold[4];
#pragma unroll
    for (int r_ = 0; r_ < 4; ++r_) {
        hold[r_] = path_state[(size_t)(p0 + q * 4 + r_) * 64 + d];
        Hb0[q * 4 + r_][d] = f2bf(hold[r_]);
    }
    __syncthreads();

    short8b aXc0 = *(const short8b*)&Xs[0][c][q * 8];
    short8b aXc1 = *(const short8b*)&Xs[0][c][32 + q * 8];

    for (int t = 0; t < TT; ++t) {
        f32x4 ax[3], ah[3];
        ax[0] = (f32x4){bz, bz, bz, bz};
        ax[1] = (f32x4){br, br, br, br};
        ax[2] = (f32x4){bxc, bxc, bxc, bxc};
        ah[0] = (f32x4){0.f, 0.f, 0.f, 0.f};
        ah[1] = (f32x4){0.f, 0.f, 0.f, 0.f};
        ah[2] = (f32x4){bhc, bhc, bhc, bhc};
        const unsigned short* hsrc = (t == 0) ? &Hb0[0][0] : &Xs[t - 1][0][0];
        short8b aH0 = *(const short8b*)(hsrc + c * 72 + q * 8);
        short8b aH1 = *(const short8b*)(hsrc + c * 72 + 32 + q * 8);
#pragma unroll
        for (int g = 0; g < 3; ++g) {
            ax[g] = __builtin_amdgcn_mfma_f32_16x16x32_bf16(aXc0, fx[g][0], ax[g], 0, 0, 0);
            ax[g] = __builtin_amdgcn_mfma_f32_16x16x32_bf16(aXc1, fx[g][1], ax[g], 0, 0, 0);
            ah[g] = __builtin_amdgcn_mfma_f32_16x16x32_bf16(aH0, fh[g][0], ah[g], 0, 0, 0);
            ah[g] = __builtin_amdgcn_mfma_f32_16x16x32_bf16(aH1, fh[g][1], ah[g], 0, 0, 0);
        }
        if (t < TT - 1) {
            aXc0 = *(const short8b*)&Xs[t + 1][c][q * 8];
            aXc1 = *(const short8b*)&Xs[t + 1][c][32 + q * 8];
        }
#pragma unroll
        for (int r_ = 0; r_ < 4; ++r_) {
            float z  = sigmoidf_(ax[0][r_] + ah[0][r_]);
            float rr = sigmoidf_(ax[1][r_] + ah[1][r_]);
            float cc = tanhf_(ax[2][r_] + rr * ah[2][r_]);
            float hn = cc + z * (hold[r_] - cc);
            hold[r_] = hn;
            Xs[t][q * 4 + r_][d] = f2bf(hn);
        }
        __syncthreads();
    }
    if (!LAST) {
#pragma unroll
        for (int r_ = 0; r_ < 4; ++r_)
            path_state[(size_t)(p0 + q * 4 + r_) * 64 + d] = hold[r_];
        {
            unsigned short* base = pssb + (size_t)p0 * TT * 64;
#pragma unroll
            for (int j = 0; j < 4; ++j) {
                int o = j * 2048 + tid * 8;
                int r = o >> 6;
                int c0 = o & 63;
                int m = r >> 3, t = r & 7;
                u32x4 v = *(const u32x4*)&Xs[t][m][c0];
                __builtin_nontemporal_store(v, (u32x4*)(base + o));
            }
        }
        return;
    }
    {
        int r = tid >> 1, hh = tid & 1;
        int m = r >> 3, t = r & 7;
        short8b rowv[8];
#pragma unroll
        for (int j = 0; j < 8; ++j)
            rowv[j] = *(const short8b*)&Xs[t][m][j * 8];
        float a1[16];
#pragma unroll
        for (int i = 0; i < 16; ++i) a1[i] = 0.f;
#pragma unroll 4
        for (int k = 0; k < 64; ++k) {
            float x = bf2f((unsigned short)rowv[k >> 3][k & 7]);
            const float* wr = &rw1s[k * 32 + hh * 16];
            float4 wa = *(const float4*)(wr);
            float4 wb = *(const float4*)(wr + 4);
            float4 wc = *(const float4*)(wr + 8);
            float4 wd = *(const float4*)(wr + 12);
            a1[0]  += x * wa.x; a1[1]  += x * wa.y; a1[2]  += x * wa.z; a1[3]  += x * wa.w;
            a1[4]  += x * wb.x; a1[5]  += x * wb.y; a1[6]  += x * wb.z; a1[7]  += x * wb.w;
            a1[8]  += x * wc.x; a1[9]  += x * wc.y; a1[10] += x * wc.z; a1[11] += x * wc.w;
            a1[12] += x * wd.x; a1[13] += x * wd.y; a1[14] += x * wd.z; a1[15] += x * wd.w;
        }
#pragma unroll
        for (int i = 0; i < 16; ++i)
            a1[i] = fmaxf(a1[i] + rb1s[hh * 16 + i], 0.0f);
        float h1[32];
#pragma unroll
        for (int i = 0; i < 16; ++i) {
            float o = __shfl_xor(a1[i], 1);
            h1[hh * 16 + i] = a1[i];
            h1[(1 - hh) * 16 + i] = o;
        }
        float a2[8];
#pragma unroll
        for (int i = 0; i < 8; ++i) a2[i] = 0.f;
#pragma unroll 4
        for (int k = 0; k < 32; ++k) {
            float x = h1[k];
            const float* wr = &rw2s[k * 16 + hh * 8];
            float4 wa = *(const float4*)(wr);
            float4 wb = *(const float4*)(wr + 4);
            a2[0] += x * wa.x; a2[1] += x * wa.y; a2[2] += x * wa.z; a2[3] += x * wa.w;
            a2[4] += x * wb.x; a2[5] += x * wb.y; a2[6] += x * wb.z; a2[7] += x * wb.w;
        }
#pragma unroll
        for (int i = 0; i < 8; ++i)
            a2[i] = fmaxf(a2[i] + rb2s[hh * 8 + i], 0.0f);
        float h2[16];
#pragma unroll
        for (int i = 0; i < 8; ++i) {
            float o = __shfl_xor(a2[i], 1);
            h2[hh * 8 + i] = a2[i];
            h2[(1 - hh) * 8 + i] = o;
        }
        float a3 = rb3[0];
#pragma unroll
        for (int k = 0; k < 16; ++k) a3 += h2[k] * rw3s[k];
        float occ = softplusf_(a3);
        float dcon = occ * frcp(cap[ltp[(p0 + m) * TT + t]]);
        float s = dcon;
        s += __shfl_xor(s, 2);
        s += __shfl_xor(s, 4);
        s += __shfl_xor(s, 8);
        if ((tid & 15) == 0) out[p0 + m] = s;
    }
}

template <int Kg>
__device__ __forceinline__ void edge_body(
    const unsigned short* __restrict__ wxT, const unsigned short* __restrict__ whT,
    const float* __restrict__ bx, const float* __restrict__ bh,
    const int* __restrict__ p2e, const unsigned short* __restrict__ pssb,
    float* __restrict__ state, unsigned short* __restrict__ smir, int blk)
{
    __shared__ int idxs[16 * Kg * 2];
    __shared__ __align__(16) unsigned short Ab[16][72];
    __shared__ __align__(16) unsigned short Hbs[16][72];
    __shared__ __align__(16) float Hf[16][68];
    int tid = threadIdx.x;
    int r0 = blk * 16;
    for (int i = tid; i < 16 * Kg * 2; i += 256)
        idxs[i] = p2e[(size_t)r0 * Kg * 2 + i];
    __syncthreads();
    {
        int r = tid >> 4, c4 = (tid & 15) * 4;
        int row = r0 + r;
        float4 s = {0.f, 0.f, 0.f, 0.f};
#pragma unroll
        for (int k = 0; k < Kg; ++k) {
            int pi = idxs[(r * Kg + k) * 2];
            int ti = idxs[(r * Kg + k) * 2 + 1];
            ushort4 v = *(const ushort4*)(pssb + ((size_t)pi * TT + ti - 1) * 64 + c4);
            s.x += bf2f(v.x); s.y += bf2f(v.y);
            s.z += bf2f(v.z); s.w += bf2f(v.w);
        }
        uint2 ua;
        ua.x = pk2bf(s.x, s.y); ua.y = pk2bf(s.z, s.w);
        *(uint2*)&Ab[r][c4] = ua;
        float4 hv = *(const float4*)(state + (size_t)row * 64 + c4);
        *(float4*)&Hf[r][c4] = hv;
        uint2 uh;
        uh.x = pk2bf(hv.x, hv.y); uh.y = pk2bf(hv.z, hv.w);
        *(uint2*)&Hbs[r][c4] = uh;
    }
    __syncthreads();
    int lane = tid & 63, w = tid >> 6;
    int c = lane & 15, q = lane >> 4;
    int d = 16 * w + c;
    short8b fx[3][2], fh[3][2];
#pragma unroll
    for (int g = 0; g < 3; ++g)
#pragma unroll
        for (int kt = 0; kt < 2; ++kt) {
            int off = (g * 64 + 16 * w + c) * 64 + kt * 32 + q * 8;
            fx[g][kt] = *(const short8b*)(wxT + off);
            fh[g][kt] = *(const short8b*)(whT + off);
        }
    float bz = bx[d] + bh[d];
    float br = bx[64 + d] + bh[64 + d];
    float bxc = bx[128 + d];
    float bhc = bh[128 + d];
    f32x4 ax[3], ah[3];
    ax[0] = (f32x4){bz, bz, bz, bz};
    ax[1] = (f32x4){br, br, br, br};
    ax[2] = (f32x4){bxc, bxc, bxc, bxc};
    ah[0] = (f32x4){0.f, 0.f, 0.f, 0.f};
    ah[1] = (f32x4){0.f, 0.f, 0.f, 0.f};
    ah[2] = (f32x4){bhc, bhc, bhc, bhc};
#pragma unroll
    for (int kt = 0; kt < 2; ++kt) {
        short8b aA = *(const short8b*)&Ab[c][kt * 32 + q * 8];
        short8b aH = *(const short8b*)&Hbs[c][kt * 32 + q * 8];
#pragma unroll
        for (int g = 0; g < 3; ++g) {
            ax[g] = __builtin_amdgcn_mfma_f32_16x16x32_bf16(aA, fx[g][kt], ax[g], 0, 0, 0);
            ah[g] = __builtin_amdgcn_mfma_f32_16x16x32_bf16(aH, fh[g][kt], ah[g], 0, 0, 0);
        }
    }
#pragma unroll
    for (int r = 0; r < 4; ++r) {
        int m = q * 4 + r;
        float z  = sigmoidf_(ax[0][r] + ah[0][r]);
        float rr = sigmoidf_(ax[1][r] + ah[1][r]);
        float cc = tanhf_(ax[2][r] + rr * ah[2][r]);
        float hn = cc + z * (Hf[m][d] - cc);
        state[(size_t)(r0 + m) * 64 + d] = hn;
        smir[(size_t)(r0 + m) * 64 + d] = f2bf(hn);
    }
}

__global__ __launch_bounds__(256) void k_edge_merged(
    const unsigned short* __restrict__ lwxT, const unsigned short* __restrict__ lwhT,
    const float* __restrict__ lbx, const float* __restrict__ lbh,
    const int* __restrict__ ptl,
    const unsigned short* __restrict__ dwxT, const unsigned short* __restrict__ dwhT,
    const float* __restrict__ dbx, const float* __restrict__ dbh,
    const int* __restrict__ ptn,
    const unsigned short* __restrict__ pssb,
    float* __restrict__ link_state, float* __restrict__ device_state,
    unsigned short* __restrict__ lsb, unsigned short* __restrict__ dsb)
{
    int b = blockIdx.x;
    if (b < LN / 16) {
        edge_body<KG>(lwxT, lwhT, lbx, lbh, ptl, pssb, link_state, lsb, b);
    } else {
        edge_body<K2G>(dwxT, dwhT, dbx, dbh, ptn, pssb, device_state, dsb, b - LN / 16);
    }
}

// ---------------------------------------------------------------------------
extern "C" void kernel_launch(void* const* d_in, const int* in_sizes, int n_in,
                              void* d_out, int out_size, void* d_ws, size_t ws_size,
                              hipStream_t stream) {
    KArgs A;
    A.ft    = (const float*)d_in[0];
    A.fpk   = (const float*)d_in[1];
    A.fps   = (const float*)d_in[2];
    A.cap   = (const float*)d_in[3];
    A.pe_w1 = (const float*)d_in[4];
    A.pe_b1 = (const float*)d_in[5];
    A.pe_w2 = (const float*)d_in[6];
    A.pe_b2 = (const float*)d_in[7];
    A.le_w1 = (const float*)d_in[8];
    A.le_b1 = (const float*)d_in[9];
    A.le_w2 = (const float*)d_in[10];
    A.le_b2 = (const float*)d_in[11];
    A.de_w1 = (const float*)d_in[12];
    A.de_b1 = (const float*)d_in[13];
    A.de_w2 = (const float*)d_in[14];
    A.de_b2 = (const float*)d_in[15];
    A.pgru_wx = (const float*)d_in[16];
    A.pgru_wh = (const float*)d_in[17];
    A.pgru_bx = (const float*)d_in[18];
    A.pgru_bh = (const float*)d_in[19];
    A.lgru_wx = (const float*)d_in[20];
    A.lgru_wh = (const float*)d_in[21];
    A.lgru_bx = (const float*)d_in[22];
    A.lgru_bh = (const float*)d_in[23];
    A.dgru_wx = (const float*)d_in[24];
    A.dgru_wh = (const float*)d_in[25];
    A.dgru_bx = (const float*)d_in[26];
    A.dgru_bh = (const float*)d_in[27];
    A.ro_w1 = (const float*)d_in[28];
    A.ro_b1 = (const float*)d_in[29];
    A.ro_w2 = (const float*)d_in[30];
    A.ro_b2 = (const float*)d_in[31];
    A.ro_w3 = (const float*)d_in[32];
    A.ro_b3 = (const float*)d_in[33];
    A.ltp   = (const int*)d_in[34];
    A.ntp   = (const int*)d_in[35];
    A.ptl   = (const int*)d_in[36];
    A.ptn   = (const int*)d_in[37];
    A.ltn   = (const int*)d_in[38];
    A.nodes = (const int*)d_in[39];
    A.ldt   = (const int*)d_in[40];
    A.out   = (float*)d_out;

    char* ws = (char*)d_ws;
    A.path_state = (float*)ws;      ws += (size_t)PN * 64 * 4;
    A.link_state = (float*)ws;      ws += (size_t)LN * 64 * 4;
    A.device_state = (float*)ws;    ws += (size_t)NN * 64 * 4;
    A.pssb = (unsigned short*)ws;   ws += (size_t)PN * TT * 64 * 2;
    A.lsb  = (unsigned short*)ws;   ws += (size_t)LN * 64 * 2;
    A.dsb  = (unsigned short*)ws;   ws += (size_t)NN * 64 * 2;
    A.pwxT = (unsigned short*)ws;   ws += 192 * 64 * 2;
    A.pwhT = (unsigned short*)ws;   ws += 192 * 64 * 2;
    A.lwxT = (unsigned short*)ws;   ws += 192 * 64 * 2;
    A.lwhT = (unsigned short*)ws;   ws += 192 * 64 * 2;
    A.dwxT = (unsigned short*)ws;   ws += 192 * 64 * 2;
    A.dwhT = (unsigned short*)ws;   ws += 192 * 64 * 2;
    A.bar_cnt = (unsigned*)ws;      ws += sizeof(unsigned);
    A.bar_gen = (unsigned*)ws;      ws += sizeof(unsigned);

    // Host-side occupancy query (capture-safe): fused path requires all 1024
    // blocks co-resident (4 blocks/CU). If the compiled kernel can't sustain
    // that, fall back to the known-good multi-kernel pipeline.
    int maxb = 0;
    hipError_t qerr = hipOccupancyMaxActiveBlocksPerMultiprocessor(&maxb, k_fused, 256, 0);
    bool use_fused = (qerr == hipSuccess && maxb >= 4);

    if (use_fused) {
        hipMemsetAsync(A.bar_cnt, 0, 2 * sizeof(unsigned), stream);
        k_fused<<<PN / 16, 256, 0, stream>>>(A);
        return;
    }

    // ---------------- fallback: R6 multi-kernel ----------------
    k_setup<<<1568, 256, 0, stream>>>(A.ft, A.fpk, A.fps, A.cap, A.ptl, A.ldt,
                                      A.pe_w1, A.pe_b1, A.pe_w2, A.pe_b2,
                                      A.le_w1, A.le_b1, A.le_w2, A.le_b2,
                                      A.pgru_wx, A.pgru_wh, A.lgru_wx, A.lgru_wh,
                                      A.dgru_wx, A.dgru_wh,
                                      A.pwxT, A.pwhT, A.lwxT, A.lwhT, A.dwxT, A.dwhT,
                                      A.path_state, A.link_state, A.lsb);
    k_device_encode<<<NN / 4, 256, 0, stream>>>(A.link_state, A.ltn, A.nodes, A.de_w1,
                                                A.de_b1, A.de_w2, A.de_b2,
                                                A.device_state, A.dsb);
    for (int it = 0; it < ITER - 1; ++it) {
        k_pscan<false><<<PN / 16, 256, 0, stream>>>(
            A.lsb, A.dsb, A.ltp, A.ntp, A.pwxT, A.pwhT, A.pgru_bx, A.pgru_bh,
            A.path_state, A.pssb, A.ro_w1, A.ro_b1, A.ro_w2, A.ro_b2, A.ro_w3,
            A.ro_b3, A.cap, A.out);
        k_edge_merged<<<LN / 16 + NN / 16, 256, 0, stream>>>(
            A.lwxT, A.lwhT, A.lgru_bx, A.lgru_bh, A.ptl,
            A.dwxT, A.dwhT, A.dgru_bx, A.dgru_bh, A.ptn,
            A.pssb, A.link_state, A.device_state, A.lsb, A.dsb);
    }
    k_pscan<true><<<PN / 16, 256, 0, stream>>>(
        A.lsb, A.dsb, A.ltp, A.ntp, A.pwxT, A.pwhT, A.pgru_bx, A.pgru_bh,
        A.path_state, A.pssb, A.ro_w1, A.ro_b1, A.ro_w2, A.ro_b2, A.ro_w3,
        A.ro_b3, A.cap, A.out);
}